// Round 1
// baseline (566.733 us; speedup 1.0000x reference)
//
#include <hip/hip_runtime.h>
#include <hip/hip_bf16.h>
#include <cmath>
#include <cstdint>

// Problem constants
#define B_ 4
#define T_ 2048
#define D_ 1024
#define H_ 16
#define HD_ 64
#define M_ (B_*T_)      // 8192 rows
#define NQKV_ 3072

typedef float f32x4 __attribute__((ext_vector_type(4)));
typedef __bf16 bf16x8 __attribute__((ext_vector_type(8)));
typedef __bf16 bf16x4 __attribute__((ext_vector_type(4)));

#define MFMA16(a, b, c) __builtin_amdgcn_mfma_f32_16x16x32_bf16((a), (b), (c), 0, 0, 0)

// ---------------- f32 -> bf16 vectorized convert ----------------
__global__ __launch_bounds__(256) void k_cvt_bf16(const float4* __restrict__ in,
                                                  bf16x4* __restrict__ out, int n4) {
  int i = blockIdx.x * 256 + threadIdx.x;
  if (i >= n4) return;
  float4 v = in[i];
  bf16x4 o;
  o[0] = (__bf16)v.x; o[1] = (__bf16)v.y; o[2] = (__bf16)v.z; o[3] = (__bf16)v.w;
  out[i] = o;
}

// ---------------- f32 [R][C] -> bf16 [C][R] transpose+convert ----------------
__global__ __launch_bounds__(256) void k_transpose_cvt(const float* __restrict__ in,
                                                       __bf16* __restrict__ out,
                                                       int R, int C) {
  __shared__ float tile[64][65];
  int r0 = blockIdx.y * 64, c0 = blockIdx.x * 64;
#pragma unroll
  for (int i = 0; i < 16; ++i) {
    int e = threadIdx.x + i * 256;
    int lr = e >> 6, lc = e & 63;
    tile[lr][lc] = in[(size_t)(r0 + lr) * C + c0 + lc];
  }
  __syncthreads();
#pragma unroll
  for (int i = 0; i < 16; ++i) {
    int e = threadIdx.x + i * 256;
    int lc = e >> 6, lr = e & 63;
    out[(size_t)(c0 + lc) * R + r0 + lr] = (__bf16)tile[lr][lc];
  }
}

// ---------------- bf16 GEMM: C[M][N] = A[M][K] @ Bt[N][K]^T + bias ----------------
// MODE 0: write f32 C linear.  MODE 1: scatter qkv epilogue -> Qb, Kb ([B,H,T,HD]) and Vtmp ([B*T][D]).
template <int MODE>
__global__ __launch_bounds__(256) void k_gemm(const __bf16* __restrict__ A,
                                              const __bf16* __restrict__ Bt,
                                              const float* __restrict__ bias,
                                              float* __restrict__ Cf,
                                              __bf16* __restrict__ Qb,
                                              __bf16* __restrict__ Kb,
                                              __bf16* __restrict__ Vtmp,
                                              int K, int N) {
  __shared__ __bf16 lA[128 * 32];
  __shared__ __bf16 lB[128 * 32];
  const int tid = threadIdx.x;
  const int lane = tid & 63, w = tid >> 6;
  const int wr = w >> 1, wc = w & 1;
  const int r15 = lane & 15, rg = lane >> 4;
  const int mb = blockIdx.y, nb = blockIdx.x;
  const int nk = K >> 5;

  const f32x4 zero = {0.f, 0.f, 0.f, 0.f};
  f32x4 acc[4][4];
#pragma unroll
  for (int m = 0; m < 4; ++m)
#pragma unroll
    for (int n = 0; n < 4; ++n) acc[m][n] = zero;

  // register prefetch staging: 512 16B-chunks per tile, 2 per thread
  int rowS[2], offS[2];
  bf16x8 pa[2], pb[2];
#pragma unroll
  for (int rep = 0; rep < 2; ++rep) {
    int c = tid + rep * 256;
    rowS[rep] = c >> 2;
    offS[rep] = (c & 3) * 8;
    pa[rep] = *(const bf16x8*)(A + (size_t)(mb * 128 + rowS[rep]) * K + offS[rep]);
    pb[rep] = *(const bf16x8*)(Bt + (size_t)(nb * 128 + rowS[rep]) * K + offS[rep]);
  }

  for (int kb = 0; kb < nk; ++kb) {
    __syncthreads();  // prior compute's LDS reads complete
#pragma unroll
    for (int rep = 0; rep < 2; ++rep) {
      *(bf16x8*)(&lA[rowS[rep] * 32 + offS[rep]]) = pa[rep];
      *(bf16x8*)(&lB[rowS[rep] * 32 + offS[rep]]) = pb[rep];
    }
    __syncthreads();
    if (kb + 1 < nk) {
#pragma unroll
      for (int rep = 0; rep < 2; ++rep) {
        pa[rep] = *(const bf16x8*)(A + (size_t)(mb * 128 + rowS[rep]) * K + (kb + 1) * 32 + offS[rep]);
        pb[rep] = *(const bf16x8*)(Bt + (size_t)(nb * 128 + rowS[rep]) * K + (kb + 1) * 32 + offS[rep]);
      }
    }
    bf16x8 af[4], bfr[4];
#pragma unroll
    for (int m = 0; m < 4; ++m)
      af[m] = *(const bf16x8*)(&lA[(wr * 64 + m * 16 + r15) * 32 + rg * 8]);
#pragma unroll
    for (int n = 0; n < 4; ++n)
      bfr[n] = *(const bf16x8*)(&lB[(wc * 64 + n * 16 + r15) * 32 + rg * 8]);
#pragma unroll
    for (int m = 0; m < 4; ++m)
#pragma unroll
      for (int n = 0; n < 4; ++n)
        acc[m][n] = MFMA16(af[m], bfr[n], acc[m][n]);
  }

  const int row0 = mb * 128 + wr * 64;
  const int col0 = nb * 128 + wc * 64;
#pragma unroll
  for (int m = 0; m < 4; ++m) {
#pragma unroll
    for (int n = 0; n < 4; ++n) {
#pragma unroll
      for (int j = 0; j < 4; ++j) {
        int r = row0 + m * 16 + rg * 4 + j;
        int c = col0 + n * 16 + r15;
        float v = acc[m][n][j] + bias[c];
        if (MODE == 0) {
          Cf[(size_t)r * N + c] = v;
        } else {
          __bf16 bv = (__bf16)v;
          int which = c >> 10, cc = c & 1023;
          int b = r >> 11, t = r & 2047;
          if (which == 0) {
            int hh = cc >> 6, hd = cc & 63;
            Qb[((size_t)(b * H_ + hh) * T_ + t) * HD_ + hd] = bv;
          } else if (which == 1) {
            int hh = cc >> 6, hd = cc & 63;
            Kb[((size_t)(b * H_ + hh) * T_ + t) * HD_ + hd] = bv;
          } else {
            Vtmp[(size_t)r * D_ + cc] = bv;
          }
        }
      }
    }
  }
}

// ---------------- V transpose: Vtmp [B*T][D] -> Vt [B,H,HD,T] ----------------
__global__ __launch_bounds__(256) void k_vtrans(const __bf16* __restrict__ Vtmp,
                                                __bf16* __restrict__ Vt) {
  __shared__ __bf16 tile[64][72];  // 144B row stride, 16B aligned
  const int bh = blockIdx.y;
  const int b = bh >> 4, h = bh & 15;
  const int t0 = blockIdx.x * 64;
  const int tid = threadIdx.x;
#pragma unroll
  for (int i = 0; i < 2; ++i) {
    int e = tid + i * 256;
    int tr = e >> 3, c8 = (e & 7) * 8;
    bf16x8 v = *(const bf16x8*)(Vtmp + (size_t)(b * T_ + t0 + tr) * D_ + h * HD_ + c8);
    *(bf16x8*)(&tile[tr][c8]) = v;
  }
  __syncthreads();
  const int hr = tid >> 2, tc0 = (tid & 3) * 16;
#pragma unroll
  for (int half = 0; half < 2; ++half) {
    bf16x8 o;
#pragma unroll
    for (int i = 0; i < 8; ++i) o[i] = tile[tc0 + half * 8 + i][hr];
    *(bf16x8*)(Vt + ((size_t)bh * HD_ + hr) * T_ + t0 + tc0 + half * 8) = o;
  }
}

// ---------------- flash attention (causal), per-wave 16 q rows ----------------
__global__ __launch_bounds__(256) void k_attn(const __bf16* __restrict__ Qb,
                                              const __bf16* __restrict__ Kb,
                                              const __bf16* __restrict__ Vt,
                                              __bf16* __restrict__ Obuf) {
  __shared__ __bf16 plds[4][16][40];  // per-wave P tile, padded rows (80B) for bank spread
  const int tid = threadIdx.x;
  const int lane = tid & 63, w = tid >> 6;
  const int r15 = lane & 15, rg = lane >> 4;
  const int bh = blockIdx.y;
  const int b = bh >> 4, h = bh & 15;
  const int q0 = blockIdx.x * 64 + w * 16;
  const __bf16* Qh = Qb + (size_t)bh * T_ * HD_;
  const __bf16* Kh = Kb + (size_t)bh * T_ * HD_;
  const __bf16* Vh = Vt + (size_t)bh * HD_ * T_;

  // hoist Q fragments (16 rows x 64 hd)
  bf16x8 qf0 = *(const bf16x8*)(Qh + (size_t)(q0 + r15) * HD_ + rg * 8);
  bf16x8 qf1 = *(const bf16x8*)(Qh + (size_t)(q0 + r15) * HD_ + 32 + rg * 8);

  float mrun[4], lrun[4];
  f32x4 acc[4];
  const f32x4 zero = {0.f, 0.f, 0.f, 0.f};
#pragma unroll
  for (int j = 0; j < 4; ++j) { mrun[j] = -INFINITY; lrun[j] = 0.f; }
#pragma unroll
  for (int t = 0; t < 4; ++t) acc[t] = zero;

  for (int kv = 0; kv < q0 + 16; kv += 32) {
    f32x4 s0 = zero, s1 = zero;
    {
      const __bf16* kp = Kh + (size_t)(kv + r15) * HD_ + rg * 8;
      s0 = MFMA16(qf0, *(const bf16x8*)kp, s0);
      s0 = MFMA16(qf1, *(const bf16x8*)(kp + 32), s0);
      const __bf16* kp2 = Kh + (size_t)(kv + 16 + r15) * HD_ + rg * 8;
      s1 = MFMA16(qf0, *(const bf16x8*)kp2, s1);
      s1 = MFMA16(qf1, *(const bf16x8*)(kp2 + 32), s1);
    }
#pragma unroll
    for (int j = 0; j < 4; ++j) {
      int row = q0 + rg * 4 + j;
      float v0 = s0[j] * 0.125f, v1 = s1[j] * 0.125f;
      if (kv + r15 > row) v0 = -INFINITY;
      if (kv + 16 + r15 > row) v1 = -INFINITY;
      float mx = fmaxf(v0, v1);
#pragma unroll
      for (int d = 1; d < 16; d <<= 1) mx = fmaxf(mx, __shfl_xor(mx, d, 64));
      float mnew = fmaxf(mrun[j], mx);
      float scale = __expf(mrun[j] - mnew);  // -inf on first tile -> 0
      float p0 = __expf(v0 - mnew);
      float p1 = __expf(v1 - mnew);
      float rs = p0 + p1;
#pragma unroll
      for (int d = 1; d < 16; d <<= 1) rs += __shfl_xor(rs, d, 64);
      lrun[j] = lrun[j] * scale + rs;
      mrun[j] = mnew;
#pragma unroll
      for (int t = 0; t < 4; ++t) acc[t][j] *= scale;
      plds[w][rg * 4 + j][r15] = (__bf16)p0;
      plds[w][rg * 4 + j][16 + r15] = (__bf16)p1;
    }
    // PV: A-frag from P_lds (same-wave RAW; compiler inserts lgkmcnt wait)
    bf16x8 pf = *(const bf16x8*)(&plds[w][r15][rg * 8]);
#pragma unroll
    for (int t = 0; t < 4; ++t) {
      bf16x8 vf = *(const bf16x8*)(Vh + (size_t)(t * 16 + r15) * T_ + kv + rg * 8);
      acc[t] = MFMA16(pf, vf, acc[t]);
    }
  }

#pragma unroll
  for (int t = 0; t < 4; ++t)
#pragma unroll
    for (int j = 0; j < 4; ++j) {
      int row = q0 + rg * 4 + j;
      int col = h * HD_ + t * 16 + r15;
      Obuf[(size_t)(b * T_ + row) * D_ + col] = (__bf16)(acc[t][j] / lrun[j]);
    }
}

// ---------------- launcher ----------------
extern "C" void kernel_launch(void* const* d_in, const int* in_sizes, int n_in,
                              void* d_out, int out_size, void* d_ws, size_t ws_size,
                              hipStream_t stream) {
  const float* x      = (const float*)d_in[0];
  const float* W_qkv  = (const float*)d_in[1];
  const float* b_qkv  = (const float*)d_in[2];
  const float* W_proj = (const float*)d_in[3];
  const float* b_proj = (const float*)d_in[4];
  float* out = (float*)d_out;

  // workspace layout (~109 MB total)
  char* ws = (char*)d_ws;
  size_t o = 0;
  __bf16* xb     = (__bf16*)(ws + o); o += (size_t)M_ * D_ * 2;       // 16.8M
  __bf16* wqkvt  = (__bf16*)(ws + o); o += (size_t)NQKV_ * D_ * 2;    // 6.3M
  __bf16* wprojt = (__bf16*)(ws + o); o += (size_t)D_ * D_ * 2;       // 2.1M
  __bf16* Qb     = (__bf16*)(ws + o); o += (size_t)M_ * D_ * 2;
  __bf16* Kb     = (__bf16*)(ws + o); o += (size_t)M_ * D_ * 2;
  __bf16* Vtmp   = (__bf16*)(ws + o); o += (size_t)M_ * D_ * 2;
  __bf16* Vt     = (__bf16*)(ws + o); o += (size_t)M_ * D_ * 2;
  __bf16* Obuf   = (__bf16*)(ws + o); o += (size_t)M_ * D_ * 2;
  (void)ws_size; (void)in_sizes; (void)n_in; (void)out_size;

  k_cvt_bf16<<<(M_ * D_ / 4 + 255) / 256, 256, 0, stream>>>((const float4*)x, (bf16x4*)xb, M_ * D_ / 4);
  k_transpose_cvt<<<dim3(NQKV_ / 64, D_ / 64), 256, 0, stream>>>(W_qkv, wqkvt, D_, NQKV_);
  k_transpose_cvt<<<dim3(D_ / 64, D_ / 64), 256, 0, stream>>>(W_proj, wprojt, D_, D_);
  k_gemm<1><<<dim3(NQKV_ / 128, M_ / 128), 256, 0, stream>>>(xb, wqkvt, b_qkv, nullptr, Qb, Kb, Vtmp, D_, NQKV_);
  k_vtrans<<<dim3(T_ / 64, B_ * H_), 256, 0, stream>>>(Vtmp, Vt);
  k_attn<<<dim3(T_ / 64, B_ * H_), 256, 0, stream>>>(Qb, Kb, Vt, Obuf);
  k_gemm<0><<<dim3(D_ / 128, M_ / 128), 256, 0, stream>>>(Obuf, wprojt, b_proj, out, nullptr, nullptr, nullptr, D_, D_);
}

// Round 2
// 364.397 us; speedup vs baseline: 1.5553x; 1.5553x over previous
//
#include <hip/hip_runtime.h>
#include <hip/hip_bf16.h>
#include <cmath>
#include <cstdint>
#include <type_traits>

// Problem constants
#define B_ 4
#define T_ 2048
#define D_ 1024
#define H_ 16
#define HD_ 64
#define M_ (B_*T_)      // 8192 rows
#define NQKV_ 3072
#define QT_ (T_/64)     // 32 q-tiles of 64 rows

typedef float f32x4 __attribute__((ext_vector_type(4)));
typedef __bf16 bf16x8 __attribute__((ext_vector_type(8)));
typedef __bf16 bf16x4 __attribute__((ext_vector_type(4)));

#define MFMA16(a, b, c) __builtin_amdgcn_mfma_f32_16x16x32_bf16((a), (b), (c), 0, 0, 0)

#if defined(__has_builtin)
#if __has_builtin(__builtin_amdgcn_global_load_lds)
#define HAVE_GLDS 1
#endif
#endif

#ifdef HAVE_GLDS
#define GLDS16(g, l) __builtin_amdgcn_global_load_lds( \
    (const __attribute__((address_space(1))) void*)(g), \
    (__attribute__((address_space(3))) void*)(l), 16, 0, 0)
#endif

__device__ inline uint32_t pack2bf(float a, float b) {
  union { __bf16 h[2]; uint32_t u; } x;
  x.h[0] = (__bf16)a; x.h[1] = (__bf16)b;
  return x.u;
}

// ---------------- f32 -> bf16 vectorized convert ----------------
__global__ __launch_bounds__(256) void k_cvt_bf16(const float4* __restrict__ in,
                                                  bf16x4* __restrict__ out, int n4) {
  int i = blockIdx.x * 256 + threadIdx.x;
  if (i >= n4) return;
  float4 v = in[i];
  bf16x4 o;
  o[0] = (__bf16)v.x; o[1] = (__bf16)v.y; o[2] = (__bf16)v.z; o[3] = (__bf16)v.w;
  out[i] = o;
}

// ---------------- f32 [R][C] -> bf16 [C][R] transpose+convert ----------------
__global__ __launch_bounds__(256) void k_transpose_cvt(const float* __restrict__ in,
                                                       __bf16* __restrict__ out,
                                                       int R, int C) {
  __shared__ float tile[64][65];
  int r0 = blockIdx.y * 64, c0 = blockIdx.x * 64;
#pragma unroll
  for (int i = 0; i < 16; ++i) {
    int e = threadIdx.x + i * 256;
    int lr = e >> 6, lc = e & 63;
    tile[lr][lc] = in[(size_t)(r0 + lr) * C + c0 + lc];
  }
  __syncthreads();
#pragma unroll
  for (int i = 0; i < 16; ++i) {
    int e = threadIdx.x + i * 256;
    int lc = e >> 6, lr = e & 63;
    out[(size_t)(c0 + lc) * R + r0 + lr] = (__bf16)tile[lr][lc];
  }
}

// ---------------- bf16 GEMM: C[M][N] = A[M][K] @ Bt[N][K]^T + bias ----------------
// MODE 0: write f32 C linear.  MODE 1: scatter qkv epilogue -> Qb, Kb ([B,H,T,HD]) and Vtmp ([B*T][D]).
template <int MODE>
__global__ __launch_bounds__(256) void k_gemm(const __bf16* __restrict__ A,
                                              const __bf16* __restrict__ Bt,
                                              const float* __restrict__ bias,
                                              float* __restrict__ Cf,
                                              __bf16* __restrict__ Qb,
                                              __bf16* __restrict__ Kb,
                                              __bf16* __restrict__ Vtmp,
                                              int K, int N) {
  __shared__ __bf16 lA[128 * 32];
  __shared__ __bf16 lB[128 * 32];
  const int tid = threadIdx.x;
  const int lane = tid & 63, w = tid >> 6;
  const int wr = w >> 1, wc = w & 1;
  const int r15 = lane & 15, rg = lane >> 4;
  const int mb = blockIdx.y, nb = blockIdx.x;
  const int nk = K >> 5;

  const f32x4 zero = {0.f, 0.f, 0.f, 0.f};
  f32x4 acc[4][4];
#pragma unroll
  for (int m = 0; m < 4; ++m)
#pragma unroll
    for (int n = 0; n < 4; ++n) acc[m][n] = zero;

  // staging geometry: 512 16B-chunks per 128x32 tile, 2 per thread
  const int c0 = tid, c1 = tid + 256;
  const int rowA0 = c0 >> 2, offA0 = (c0 & 3) * 8;
  const int rowA1 = c1 >> 2, offA1 = (c1 & 3) * 8;
  const __bf16* Ab = A + (size_t)(mb * 128) * K;
  const __bf16* Bb = Bt + (size_t)(nb * 128) * K;

  for (int kb = 0; kb < nk; ++kb) {
    __syncthreads();  // prior compute's LDS reads complete before overwrite
#ifdef HAVE_GLDS
    GLDS16(Ab + (size_t)rowA0 * K + kb * 32 + offA0, &lA[c0 * 8]);
    GLDS16(Ab + (size_t)rowA1 * K + kb * 32 + offA1, &lA[c1 * 8]);
    GLDS16(Bb + (size_t)rowA0 * K + kb * 32 + offA0, &lB[c0 * 8]);
    GLDS16(Bb + (size_t)rowA1 * K + kb * 32 + offA1, &lB[c1 * 8]);
#else
    {
      bf16x8 ta0 = *(const bf16x8*)(Ab + (size_t)rowA0 * K + kb * 32 + offA0);
      bf16x8 ta1 = *(const bf16x8*)(Ab + (size_t)rowA1 * K + kb * 32 + offA1);
      bf16x8 tb0 = *(const bf16x8*)(Bb + (size_t)rowA0 * K + kb * 32 + offA0);
      bf16x8 tb1 = *(const bf16x8*)(Bb + (size_t)rowA1 * K + kb * 32 + offA1);
      *(bf16x8*)(&lA[c0 * 8]) = ta0;
      *(bf16x8*)(&lA[c1 * 8]) = ta1;
      *(bf16x8*)(&lB[c0 * 8]) = tb0;
      *(bf16x8*)(&lB[c1 * 8]) = tb1;
    }
#endif
    __syncthreads();  // staging visible (compiler drains vmcnt before barrier)
    bf16x8 af[4], bfr[4];
#pragma unroll
    for (int m = 0; m < 4; ++m)
      af[m] = *(const bf16x8*)(&lA[(wr * 64 + m * 16 + r15) * 32 + rg * 8]);
#pragma unroll
    for (int n = 0; n < 4; ++n)
      bfr[n] = *(const bf16x8*)(&lB[(wc * 64 + n * 16 + r15) * 32 + rg * 8]);
#pragma unroll
    for (int m = 0; m < 4; ++m)
#pragma unroll
      for (int n = 0; n < 4; ++n)
        acc[m][n] = MFMA16(af[m], bfr[n], acc[m][n]);
  }

  const int row0 = mb * 128 + wr * 64;
  const int col0 = nb * 128 + wc * 64;
#pragma unroll
  for (int m = 0; m < 4; ++m) {
#pragma unroll
    for (int n = 0; n < 4; ++n) {
#pragma unroll
      for (int j = 0; j < 4; ++j) {
        int r = row0 + m * 16 + rg * 4 + j;
        int c = col0 + n * 16 + r15;
        float v = acc[m][n][j] + bias[c];
        if (MODE == 0) {
          Cf[(size_t)r * N + c] = v;
        } else {
          __bf16 bv = (__bf16)v;
          int which = c >> 10, cc = c & 1023;
          int b = r >> 11, t = r & 2047;
          if (which == 0) {
            int hh = cc >> 6, hd = cc & 63;
            Qb[((size_t)(b * H_ + hh) * T_ + t) * HD_ + hd] = bv;
          } else if (which == 1) {
            int hh = cc >> 6, hd = cc & 63;
            Kb[((size_t)(b * H_ + hh) * T_ + t) * HD_ + hd] = bv;
          } else {
            Vtmp[(size_t)r * D_ + cc] = bv;
          }
        }
      }
    }
  }
}

// ---------------- V transpose: Vtmp [B*T][D] -> Vt [B,H,HD,T] ----------------
__global__ __launch_bounds__(256) void k_vtrans(const __bf16* __restrict__ Vtmp,
                                                __bf16* __restrict__ Vt) {
  __shared__ __bf16 tile[64][72];  // 144B row stride, 16B aligned
  const int bh = blockIdx.y;
  const int b = bh >> 4, h = bh & 15;
  const int t0 = blockIdx.x * 64;
  const int tid = threadIdx.x;
#pragma unroll
  for (int i = 0; i < 2; ++i) {
    int e = tid + i * 256;
    int tr = e >> 3, c8 = (e & 7) * 8;
    bf16x8 v = *(const bf16x8*)(Vtmp + (size_t)(b * T_ + t0 + tr) * D_ + h * HD_ + c8);
    *(bf16x8*)(&tile[tr][c8]) = v;
  }
  __syncthreads();
  const int hr = tid >> 2, tc0 = (tid & 3) * 16;
#pragma unroll
  for (int half = 0; half < 2; ++half) {
    bf16x8 o;
#pragma unroll
    for (int i = 0; i < 8; ++i) o[i] = tile[tc0 + half * 8 + i][hr];
    *(bf16x8*)(Vt + ((size_t)bh * HD_ + hr) * T_ + t0 + tc0 + half * 8) = o;
  }
}

// ---------------- flash attention (causal), swapped QK^T, paired q-tiles ----------------
// grid: (QT_/2, B*H). Block x handles q-tiles x and (QT_-1-x): constant work.
// Swapped scores: S^T = mfma(K_frag, Q_frag) -> lane holds 8 scores of q-row (lane&15).
__global__ __launch_bounds__(256) void k_attn(const __bf16* __restrict__ Qb,
                                              const __bf16* __restrict__ Kb,
                                              const __bf16* __restrict__ Vt,
                                              __bf16* __restrict__ Obuf) {
  __shared__ __bf16 plds[4][16][40];  // per-wave P tile (P[q][kv]), 80B row stride
  const int tid = threadIdx.x;
  const int lane = tid & 63, w = tid >> 6;
  const int r15 = lane & 15, rg = lane >> 4;
  const int bh = blockIdx.y;
  const int b = bh >> 4, h = bh & 15;
  const __bf16* Qh = Qb + (size_t)bh * T_ * HD_;
  const __bf16* Kh = Kb + (size_t)bh * T_ * HD_;
  const __bf16* Vh = Vt + (size_t)bh * HD_ * T_;
  const f32x4 zero = {0.f, 0.f, 0.f, 0.f};

#pragma unroll
  for (int half = 0; half < 2; ++half) {
    const int qt = half ? (QT_ - 1 - blockIdx.x) : blockIdx.x;
    const int q0 = qt * 64 + w * 16;

    // Q fragments (B-operand: col = q = r15, k = rg*8..), 1/sqrt(HD) folded in (exact pow2)
    bf16x8 qf0 = *(const bf16x8*)(Qh + (size_t)(q0 + r15) * HD_ + rg * 8);
    bf16x8 qf1 = *(const bf16x8*)(Qh + (size_t)(q0 + r15) * HD_ + 32 + rg * 8);
#pragma unroll
    for (int i = 0; i < 8; ++i) {
      qf0[i] = (__bf16)((float)qf0[i] * 0.125f);
      qf1[i] = (__bf16)((float)qf1[i] * 0.125f);
    }

    float mrun = -INFINITY, lrun = 0.f;
    f32x4 acc[4];
#pragma unroll
    for (int t = 0; t < 4; ++t) acc[t] = zero;

    auto run_tile = [&](int kv, auto maskc) {
      constexpr bool MASKED = decltype(maskc)::value;
      // K A-frags: rows = kv .. kv+31 (two 16-row groups)
      const __bf16* kp0 = Kh + (size_t)(kv + r15) * HD_ + rg * 8;
      const __bf16* kp1 = Kh + (size_t)(kv + 16 + r15) * HD_ + rg * 8;
      bf16x8 ka0 = *(const bf16x8*)kp0;
      bf16x8 ka1 = *(const bf16x8*)(kp0 + 32);
      bf16x8 kb0 = *(const bf16x8*)kp1;
      bf16x8 kb1 = *(const bf16x8*)(kp1 + 32);
      // V B-frags for PV (col = d, k = kv offset)
      bf16x8 vf0 = *(const bf16x8*)(Vh + (size_t)(0 * 16 + r15) * T_ + kv + rg * 8);
      bf16x8 vf1 = *(const bf16x8*)(Vh + (size_t)(1 * 16 + r15) * T_ + kv + rg * 8);
      bf16x8 vf2 = *(const bf16x8*)(Vh + (size_t)(2 * 16 + r15) * T_ + kv + rg * 8);
      bf16x8 vf3 = *(const bf16x8*)(Vh + (size_t)(3 * 16 + r15) * T_ + kv + rg * 8);

      f32x4 s0 = zero, s1 = zero;   // S^T: row = kv (rg*4+j), col = q (r15)
      s0 = MFMA16(ka0, qf0, s0);
      s1 = MFMA16(kb0, qf0, s1);
      s0 = MFMA16(ka1, qf1, s0);
      s1 = MFMA16(kb1, qf1, s1);

      float p[8];
      float m8 = -INFINITY;
#pragma unroll
      for (int j = 0; j < 4; ++j) {
        float v0 = s0[j], v1 = s1[j];
        if (MASKED) {
          if (kv + rg * 4 + j > q0 + r15) v0 = -INFINITY;
          if (kv + 16 + rg * 4 + j > q0 + r15) v1 = -INFINITY;
        }
        p[j] = v0; p[4 + j] = v1;
        m8 = fmaxf(m8, fmaxf(v0, v1));
      }
      // cross-group reduce: rows of same q across 4 rg groups
      m8 = fmaxf(m8, __shfl_xor(m8, 16, 64));
      m8 = fmaxf(m8, __shfl_xor(m8, 32, 64));
      float mnew = fmaxf(mrun, m8);
      float scale = __expf(mrun - mnew);  // first tile: exp(-inf)=0
      float rs = 0.f;
#pragma unroll
      for (int i = 0; i < 8; ++i) { p[i] = __expf(p[i] - mnew); rs += p[i]; }
      rs += __shfl_xor(rs, 16, 64);
      rs += __shfl_xor(rs, 32, 64);
      lrun = lrun * scale + rs;
      mrun = mnew;

      // P^T in regs -> P[q][kv] in LDS (packed u32 writes)
      *(uint32_t*)(&plds[w][r15][rg * 4 + 0])      = pack2bf(p[0], p[1]);
      *(uint32_t*)(&plds[w][r15][rg * 4 + 2])      = pack2bf(p[2], p[3]);
      *(uint32_t*)(&plds[w][r15][16 + rg * 4 + 0]) = pack2bf(p[4], p[5]);
      *(uint32_t*)(&plds[w][r15][16 + rg * 4 + 2]) = pack2bf(p[6], p[7]);

      // rescale acc: scale for q-row (rg*4+j) lives in lane (rg*4+j)
#pragma unroll
      for (int j = 0; j < 4; ++j) {
        float scj = __shfl(scale, rg * 4 + j, 64);
        acc[0][j] *= scj; acc[1][j] *= scj; acc[2][j] *= scj; acc[3][j] *= scj;
      }

      bf16x8 pf = *(const bf16x8*)(&plds[w][r15][rg * 8]);  // A-frag: row=q, k=kv
      acc[0] = MFMA16(pf, vf0, acc[0]);
      acc[1] = MFMA16(pf, vf1, acc[1]);
      acc[2] = MFMA16(pf, vf2, acc[2]);
      acc[3] = MFMA16(pf, vf3, acc[3]);
    };

    const int nfull = q0 >> 5;          // unmasked 32-kv tiles
    for (int t = 0; t < nfull; ++t) run_tile(t * 32, std::false_type{});
    run_tile(nfull * 32, std::true_type{});  // exactly one masked tile

    // epilogue: O[q][d], q-row = rg*4+j -> lrun from lane (rg*4+j)
#pragma unroll
    for (int j = 0; j < 4; ++j) {
      float lj = __shfl(lrun, rg * 4 + j, 64);
      float inv = 1.0f / lj;
      int row = q0 + rg * 4 + j;
#pragma unroll
      for (int t = 0; t < 4; ++t) {
        int col = h * HD_ + t * 16 + r15;
        Obuf[(size_t)(b * T_ + row) * D_ + col] = (__bf16)(acc[t][j] * inv);
      }
    }
  }
}

// ---------------- launcher ----------------
extern "C" void kernel_launch(void* const* d_in, const int* in_sizes, int n_in,
                              void* d_out, int out_size, void* d_ws, size_t ws_size,
                              hipStream_t stream) {
  const float* x      = (const float*)d_in[0];
  const float* W_qkv  = (const float*)d_in[1];
  const float* b_qkv  = (const float*)d_in[2];
  const float* W_proj = (const float*)d_in[3];
  const float* b_proj = (const float*)d_in[4];
  float* out = (float*)d_out;

  char* ws = (char*)d_ws;
  size_t o = 0;
  __bf16* xb     = (__bf16*)(ws + o); o += (size_t)M_ * D_ * 2;
  __bf16* wqkvt  = (__bf16*)(ws + o); o += (size_t)NQKV_ * D_ * 2;
  __bf16* wprojt = (__bf16*)(ws + o); o += (size_t)D_ * D_ * 2;
  __bf16* Qb     = (__bf16*)(ws + o); o += (size_t)M_ * D_ * 2;
  __bf16* Kb     = (__bf16*)(ws + o); o += (size_t)M_ * D_ * 2;
  __bf16* Vtmp   = (__bf16*)(ws + o); o += (size_t)M_ * D_ * 2;
  __bf16* Vt     = (__bf16*)(ws + o); o += (size_t)M_ * D_ * 2;
  __bf16* Obuf   = (__bf16*)(ws + o); o += (size_t)M_ * D_ * 2;
  (void)ws_size; (void)in_sizes; (void)n_in; (void)out_size;

  k_cvt_bf16<<<(M_ * D_ / 4 + 255) / 256, 256, 0, stream>>>((const float4*)x, (bf16x4*)xb, M_ * D_ / 4);
  k_transpose_cvt<<<dim3(NQKV_ / 64, D_ / 64), 256, 0, stream>>>(W_qkv, wqkvt, D_, NQKV_);
  k_transpose_cvt<<<dim3(D_ / 64, D_ / 64), 256, 0, stream>>>(W_proj, wprojt, D_, D_);
  k_gemm<1><<<dim3(NQKV_ / 128, M_ / 128), 256, 0, stream>>>(xb, wqkvt, b_qkv, nullptr, Qb, Kb, Vtmp, D_, NQKV_);
  k_vtrans<<<dim3(T_ / 64, B_ * H_), 256, 0, stream>>>(Vtmp, Vt);
  k_attn<<<dim3(QT_ / 2, B_ * H_), 256, 0, stream>>>(Qb, Kb, Vt, Obuf);
  k_gemm<0><<<dim3(D_ / 128, M_ / 128), 256, 0, stream>>>(Obuf, wprojt, b_proj, out, nullptr, nullptr, nullptr, D_, D_);
}

// Round 3
// 363.217 us; speedup vs baseline: 1.5603x; 1.0032x over previous
//
#include <hip/hip_runtime.h>
#include <hip/hip_bf16.h>
#include <cmath>
#include <cstdint>
#include <type_traits>

// Problem constants
#define B_ 4
#define T_ 2048
#define D_ 1024
#define H_ 16
#define HD_ 64
#define M_ (B_*T_)      // 8192 rows
#define NQKV_ 3072

// Q pre-scale: 1/sqrt(HD) * log2(e)  (softmax done in exp2 domain)
#define SCALE_Q 0.18033688011112042f

typedef float f32x4 __attribute__((ext_vector_type(4)));
typedef float f32x16 __attribute__((ext_vector_type(16)));
typedef __bf16 bf16x8 __attribute__((ext_vector_type(8)));
typedef __bf16 bf16x4 __attribute__((ext_vector_type(4)));

#define MFMA16(a, b, c) __builtin_amdgcn_mfma_f32_16x16x32_bf16((a), (b), (c), 0, 0, 0)
#define MFMA32(a, b, c) __builtin_amdgcn_mfma_f32_32x32x16_bf16((a), (b), (c), 0, 0, 0)

#if defined(__has_builtin)
#if __has_builtin(__builtin_amdgcn_global_load_lds)
#define HAVE_GLDS 1
#endif
#if __has_builtin(__builtin_amdgcn_exp2f)
#define EXP2(x) __builtin_amdgcn_exp2f(x)
#endif
#endif
#ifndef EXP2
#define EXP2(x) exp2f(x)
#endif

#ifdef HAVE_GLDS
#define GLDS16(g, l) __builtin_amdgcn_global_load_lds( \
    (const __attribute__((address_space(1))) void*)(g), \
    (__attribute__((address_space(3))) void*)(l), 16, 0, 0)
#endif

__device__ inline uint32_t pack2bf(float a, float b) {
  union { __bf16 h[2]; uint32_t u; } x;
  x.h[0] = (__bf16)a; x.h[1] = (__bf16)b;
  return x.u;
}

// ---------------- f32 -> bf16 vectorized convert ----------------
__global__ __launch_bounds__(256) void k_cvt_bf16(const float4* __restrict__ in,
                                                  bf16x4* __restrict__ out, int n4) {
  int i = blockIdx.x * 256 + threadIdx.x;
  if (i >= n4) return;
  float4 v = in[i];
  bf16x4 o;
  o[0] = (__bf16)v.x; o[1] = (__bf16)v.y; o[2] = (__bf16)v.z; o[3] = (__bf16)v.w;
  out[i] = o;
}

// ---------------- f32 [R][C] -> bf16 [C][R] transpose+convert ----------------
__global__ __launch_bounds__(256) void k_transpose_cvt(const float* __restrict__ in,
                                                       __bf16* __restrict__ out,
                                                       int R, int C) {
  __shared__ float tile[64][65];
  int r0 = blockIdx.y * 64, c0 = blockIdx.x * 64;
#pragma unroll
  for (int i = 0; i < 16; ++i) {
    int e = threadIdx.x + i * 256;
    int lr = e >> 6, lc = e & 63;
    tile[lr][lc] = in[(size_t)(r0 + lr) * C + c0 + lc];
  }
  __syncthreads();
#pragma unroll
  for (int i = 0; i < 16; ++i) {
    int e = threadIdx.x + i * 256;
    int lc = e >> 6, lr = e & 63;
    out[(size_t)(c0 + lc) * R + r0 + lr] = (__bf16)tile[lr][lc];
  }
}

// ---------------- bf16 GEMM: C[M][N] = A[M][K] @ Bt[N][K]^T + bias ----------------
// MODE 0: write f32 C linear.  MODE 1: scatter qkv epilogue -> Qb (pre-scaled), Kb, Vtmp.
template <int MODE>
__global__ __launch_bounds__(256) void k_gemm(const __bf16* __restrict__ A,
                                              const __bf16* __restrict__ Bt,
                                              const float* __restrict__ bias,
                                              float* __restrict__ Cf,
                                              __bf16* __restrict__ Qb,
                                              __bf16* __restrict__ Kb,
                                              __bf16* __restrict__ Vtmp,
                                              int K, int N) {
  __shared__ __bf16 lA[128 * 32];
  __shared__ __bf16 lB[128 * 32];
  const int tid = threadIdx.x;
  const int lane = tid & 63, w = tid >> 6;
  const int wr = w >> 1, wc = w & 1;
  const int r15 = lane & 15, rg = lane >> 4;
  const int mb = blockIdx.y, nb = blockIdx.x;
  const int nk = K >> 5;

  const f32x4 zero = {0.f, 0.f, 0.f, 0.f};
  f32x4 acc[4][4];
#pragma unroll
  for (int m = 0; m < 4; ++m)
#pragma unroll
    for (int n = 0; n < 4; ++n) acc[m][n] = zero;

  const int c0 = tid, c1 = tid + 256;
  const int rowA0 = c0 >> 2, offA0 = (c0 & 3) * 8;
  const int rowA1 = c1 >> 2, offA1 = (c1 & 3) * 8;
  const __bf16* Ab = A + (size_t)(mb * 128) * K;
  const __bf16* Bb = Bt + (size_t)(nb * 128) * K;

  for (int kb = 0; kb < nk; ++kb) {
    __syncthreads();
#ifdef HAVE_GLDS
    GLDS16(Ab + (size_t)rowA0 * K + kb * 32 + offA0, &lA[c0 * 8]);
    GLDS16(Ab + (size_t)rowA1 * K + kb * 32 + offA1, &lA[c1 * 8]);
    GLDS16(Bb + (size_t)rowA0 * K + kb * 32 + offA0, &lB[c0 * 8]);
    GLDS16(Bb + (size_t)rowA1 * K + kb * 32 + offA1, &lB[c1 * 8]);
#else
    {
      bf16x8 ta0 = *(const bf16x8*)(Ab + (size_t)rowA0 * K + kb * 32 + offA0);
      bf16x8 ta1 = *(const bf16x8*)(Ab + (size_t)rowA1 * K + kb * 32 + offA1);
      bf16x8 tb0 = *(const bf16x8*)(Bb + (size_t)rowA0 * K + kb * 32 + offA0);
      bf16x8 tb1 = *(const bf16x8*)(Bb + (size_t)rowA1 * K + kb * 32 + offA1);
      *(bf16x8*)(&lA[c0 * 8]) = ta0;
      *(bf16x8*)(&lA[c1 * 8]) = ta1;
      *(bf16x8*)(&lB[c0 * 8]) = tb0;
      *(bf16x8*)(&lB[c1 * 8]) = tb1;
    }
#endif
    __syncthreads();
    bf16x8 af[4], bfr[4];
#pragma unroll
    for (int m = 0; m < 4; ++m)
      af[m] = *(const bf16x8*)(&lA[(wr * 64 + m * 16 + r15) * 32 + rg * 8]);
#pragma unroll
    for (int n = 0; n < 4; ++n)
      bfr[n] = *(const bf16x8*)(&lB[(wc * 64 + n * 16 + r15) * 32 + rg * 8]);
#pragma unroll
    for (int m = 0; m < 4; ++m)
#pragma unroll
      for (int n = 0; n < 4; ++n)
        acc[m][n] = MFMA16(af[m], bfr[n], acc[m][n]);
  }

  const int row0 = mb * 128 + wr * 64;
  const int col0 = nb * 128 + wc * 64;
#pragma unroll
  for (int m = 0; m < 4; ++m) {
#pragma unroll
    for (int n = 0; n < 4; ++n) {
#pragma unroll
      for (int j = 0; j < 4; ++j) {
        int r = row0 + m * 16 + rg * 4 + j;
        int c = col0 + n * 16 + r15;
        float v = acc[m][n][j] + bias[c];
        if (MODE == 0) {
          Cf[(size_t)r * N + c] = v;
        } else {
          int which = c >> 10, cc = c & 1023;
          int b = r >> 11, t = r & 2047;
          if (which == 0) {
            int hh = cc >> 6, hd = cc & 63;
            Qb[((size_t)(b * H_ + hh) * T_ + t) * HD_ + hd] = (__bf16)(v * SCALE_Q);
          } else if (which == 1) {
            int hh = cc >> 6, hd = cc & 63;
            Kb[((size_t)(b * H_ + hh) * T_ + t) * HD_ + hd] = (__bf16)v;
          } else {
            Vtmp[(size_t)r * D_ + cc] = (__bf16)v;
          }
        }
      }
    }
  }
}

// ---------------- V transpose: Vtmp [B*T][D] -> Vt [B,H,HD,T] ----------------
__global__ __launch_bounds__(256) void k_vtrans(const __bf16* __restrict__ Vtmp,
                                                __bf16* __restrict__ Vt) {
  __shared__ __bf16 tile[64][72];
  const int bh = blockIdx.y;
  const int b = bh >> 4, h = bh & 15;
  const int t0 = blockIdx.x * 64;
  const int tid = threadIdx.x;
#pragma unroll
  for (int i = 0; i < 2; ++i) {
    int e = tid + i * 256;
    int tr = e >> 3, c8 = (e & 7) * 8;
    bf16x8 v = *(const bf16x8*)(Vtmp + (size_t)(b * T_ + t0 + tr) * D_ + h * HD_ + c8);
    *(bf16x8*)(&tile[tr][c8]) = v;
  }
  __syncthreads();
  const int hr = tid >> 2, tc0 = (tid & 3) * 16;
#pragma unroll
  for (int half = 0; half < 2; ++half) {
    bf16x8 o;
#pragma unroll
    for (int i = 0; i < 8; ++i) o[i] = tile[tc0 + half * 8 + i][hr];
    *(bf16x8*)(Vt + ((size_t)bh * HD_ + hr) * T_ + t0 + tc0 + half * 8) = o;
  }
}

// ---------------- flash attention (causal), 32x32 swapped, in-register softmax --------
// grid (16, B*H), 4 waves/block. Wave handles one 32-row q-tile, heavy-first:
// qt = 63 - (4*bx + w). KVBLK=64. S^T = mfma32(K, Q): lane owns 32 scores of
// q-row (lane&31) split with partner lane (lane^32). No LDS, no barriers.
__global__ __launch_bounds__(256) void k_attn(const __bf16* __restrict__ Qb,
                                              const __bf16* __restrict__ Kb,
                                              const __bf16* __restrict__ Vt,
                                              __bf16* __restrict__ Obuf) {
  const int tid = threadIdx.x;
  const int lane = tid & 63, w = tid >> 6;
  const int l31 = lane & 31, hi = lane >> 5;
  const int bh = blockIdx.y;
  const int b = bh >> 4, h = bh & 15;
  const int qt = 63 - (blockIdx.x * 4 + w);
  const int q0 = qt * 32;
  const __bf16* Qh = Qb + (size_t)bh * T_ * HD_;
  const __bf16* Kh = Kb + (size_t)bh * T_ * HD_;
  const __bf16* Vh = Vt + (size_t)bh * HD_ * T_;

  // Q B-frags (col=q=l31, k = ks*16 + hi*8 + i), pre-scaled in GEMM epilogue
  bf16x8 qf[4];
#pragma unroll
  for (int ks = 0; ks < 4; ++ks)
    qf[ks] = *(const bf16x8*)(Qh + (size_t)(q0 + l31) * HD_ + ks * 16 + hi * 8);

  f32x16 o0, o1;
#pragma unroll
  for (int i = 0; i < 16; ++i) { o0[i] = 0.f; o1[i] = 0.f; }
  float mrun = -INFINITY, lrun = 0.f;
  float p[32];

  auto run_tile = [&](int kv0, auto maskc) {
    constexpr bool MASKED = decltype(maskc)::value;
    // K A-frags: row = kv0 + seg*32 + l31, k = ks*16 + hi*8 + i
    bf16x8 kf[2][4];
#pragma unroll
    for (int seg = 0; seg < 2; ++seg)
#pragma unroll
      for (int ks = 0; ks < 4; ++ks)
        kf[seg][ks] = *(const bf16x8*)(Kh + (size_t)(kv0 + seg * 32 + l31) * HD_ + ks * 16 + hi * 8);

    f32x16 s0, s1;
#pragma unroll
    for (int i = 0; i < 16; ++i) { s0[i] = 0.f; s1[i] = 0.f; }
#pragma unroll
    for (int ks = 0; ks < 4; ++ks) s0 = MFMA32(kf[0][ks], qf[ks], s0);
#pragma unroll
    for (int ks = 0; ks < 4; ++ks) s1 = MFMA32(kf[1][ks], qf[ks], s1);

    // extract, mask, row max (row = q = l31; partner lane holds other 32 kv)
    float pmax = -INFINITY;
#pragma unroll
    for (int r = 0; r < 16; ++r) {
      float v0 = s0[r], v1 = s1[r];
      if (MASKED) {
        int rr = (r & 3) + 8 * (r >> 2) + 4 * hi;
        if (kv0 + rr > q0 + l31) v0 = -INFINITY;
        if (kv0 + 32 + rr > q0 + l31) v1 = -INFINITY;
      }
      p[r] = v0; p[16 + r] = v1;
      pmax = fmaxf(pmax, fmaxf(v0, v1));
    }
    pmax = fmaxf(pmax, __shfl_xor(pmax, 32, 64));

    // defer-max (T13): only rescale when max grew past threshold
    if (__any(pmax > mrun + 8.0f)) {
      float mnew = fmaxf(mrun, pmax);
      float sc = EXP2(mrun - mnew);   // first tile: exp2(-inf) = 0
#pragma unroll
      for (int r = 0; r < 16; ++r) {
        int rr = (r & 3) + 8 * (r >> 2) + 4 * hi;
        float scr = __shfl(sc, rr, 64);
        o0[r] *= scr; o1[r] *= scr;
      }
      lrun *= sc;
      mrun = mnew;
    }
    float rs = 0.f;
#pragma unroll
    for (int i = 0; i < 32; ++i) { p[i] = EXP2(p[i] - mrun); rs += p[i]; }
    rs += __shfl_xor(rs, 32, 64);
    lrun += rs;

    // V B-frags: col = d = dh*32 + l31, k = ks*16 + hi*8 + i
    bf16x8 vf[2][4];
#pragma unroll
    for (int dh = 0; dh < 2; ++dh)
#pragma unroll
      for (int ks = 0; ks < 4; ++ks)
        vf[dh][ks] = *(const bf16x8*)(Vh + (size_t)(dh * 32 + l31) * T_ + kv0 + ks * 16 + hi * 8);

    // P repack -> A-frags (in-register, partner exchange via shfl_xor 32)
#pragma unroll
    for (int ks = 0; ks < 4; ++ks) {
      const int base = 16 * (ks >> 1) + 8 * (ks & 1);
      uint32_t w0 = pack2bf(p[base + 0], p[base + 1]);
      uint32_t w1 = pack2bf(p[base + 2], p[base + 3]);
      uint32_t w2 = pack2bf(p[base + 4], p[base + 5]);
      uint32_t w3 = pack2bf(p[base + 6], p[base + 7]);
      uint32_t sx = hi ? w0 : w2;
      uint32_t sy = hi ? w1 : w3;
      uint32_t px = (uint32_t)__shfl_xor((int)sx, 32, 64);
      uint32_t py = (uint32_t)__shfl_xor((int)sy, 32, 64);
      union { uint32_t u[4]; bf16x8 v; } pa;
      pa.u[0] = hi ? px : w0;
      pa.u[1] = hi ? py : w1;
      pa.u[2] = hi ? w2 : px;
      pa.u[3] = hi ? w3 : py;
      o0 = MFMA32(pa.v, vf[0][ks], o0);
      o1 = MFMA32(pa.v, vf[1][ks], o1);
    }
  };

  const int nfull = q0 >> 6;
  for (int t = 0; t < nfull; ++t) run_tile(t * 64, std::false_type{});
  run_tile(nfull * 64, std::true_type{});

  // epilogue: row q' = rr(r,hi), col d = l31 (+32)
#pragma unroll
  for (int r = 0; r < 16; ++r) {
    int rr = (r & 3) + 8 * (r >> 2) + 4 * hi;
    float inv = 1.0f / __shfl(lrun, rr, 64);
    int row = q0 + rr;
    __bf16* op = Obuf + (size_t)(b * T_ + row) * D_ + h * HD_ + l31;
    op[0]  = (__bf16)(o0[r] * inv);
    op[32] = (__bf16)(o1[r] * inv);
  }
}

// ---------------- launcher ----------------
extern "C" void kernel_launch(void* const* d_in, const int* in_sizes, int n_in,
                              void* d_out, int out_size, void* d_ws, size_t ws_size,
                              hipStream_t stream) {
  const float* x      = (const float*)d_in[0];
  const float* W_qkv  = (const float*)d_in[1];
  const float* b_qkv  = (const float*)d_in[2];
  const float* W_proj = (const float*)d_in[3];
  const float* b_proj = (const float*)d_in[4];
  float* out = (float*)d_out;

  char* ws = (char*)d_ws;
  size_t o = 0;
  __bf16* xb     = (__bf16*)(ws + o); o += (size_t)M_ * D_ * 2;
  __bf16* wqkvt  = (__bf16*)(ws + o); o += (size_t)NQKV_ * D_ * 2;
  __bf16* wprojt = (__bf16*)(ws + o); o += (size_t)D_ * D_ * 2;
  __bf16* Qb     = (__bf16*)(ws + o); o += (size_t)M_ * D_ * 2;
  __bf16* Kb     = (__bf16*)(ws + o); o += (size_t)M_ * D_ * 2;
  __bf16* Vtmp   = (__bf16*)(ws + o); o += (size_t)M_ * D_ * 2;
  __bf16* Vt     = (__bf16*)(ws + o); o += (size_t)M_ * D_ * 2;
  __bf16* Obuf   = (__bf16*)(ws + o); o += (size_t)M_ * D_ * 2;
  (void)ws_size; (void)in_sizes; (void)n_in; (void)out_size;

  k_cvt_bf16<<<(M_ * D_ / 4 + 255) / 256, 256, 0, stream>>>((const float4*)x, (bf16x4*)xb, M_ * D_ / 4);
  k_transpose_cvt<<<dim3(NQKV_ / 64, D_ / 64), 256, 0, stream>>>(W_qkv, wqkvt, D_, NQKV_);
  k_transpose_cvt<<<dim3(D_ / 64, D_ / 64), 256, 0, stream>>>(W_proj, wprojt, D_, D_);
  k_gemm<1><<<dim3(NQKV_ / 128, M_ / 128), 256, 0, stream>>>(xb, wqkvt, b_qkv, nullptr, Qb, Kb, Vtmp, D_, NQKV_);
  k_vtrans<<<dim3(T_ / 64, B_ * H_), 256, 0, stream>>>(Vtmp, Vt);
  k_attn<<<dim3(16, B_ * H_), 256, 0, stream>>>(Qb, Kb, Vt, Obuf);
  k_gemm<0><<<dim3(D_ / 128, M_ / 128), 256, 0, stream>>>(Obuf, wprojt, b_proj, out, nullptr, nullptr, nullptr, D_, D_);
}

// Round 4
// 213.604 us; speedup vs baseline: 2.6532x; 1.7004x over previous
//
#include <hip/hip_runtime.h>
#include <hip/hip_bf16.h>
#include <cmath>
#include <cstdint>
#include <type_traits>

// Problem constants
#define B_ 4
#define T_ 2048
#define D_ 1024
#define H_ 16
#define HD_ 64
#define M_ (B_*T_)      // 8192 rows
#define NQKV_ 3072

// Q pre-scale: 1/sqrt(HD) * log2(e)  (softmax done in exp2 domain)
#define SCALE_Q 0.18033688011112042f

typedef float f32x4 __attribute__((ext_vector_type(4)));
typedef float f32x16 __attribute__((ext_vector_type(16)));
typedef __bf16 bf16x8 __attribute__((ext_vector_type(8)));
typedef __bf16 bf16x4 __attribute__((ext_vector_type(4)));

#define MFMA16(a, b, c) __builtin_amdgcn_mfma_f32_16x16x32_bf16((a), (b), (c), 0, 0, 0)
#define MFMA32(a, b, c) __builtin_amdgcn_mfma_f32_32x32x16_bf16((a), (b), (c), 0, 0, 0)

#if defined(__has_builtin)
#if __has_builtin(__builtin_amdgcn_global_load_lds)
#define HAVE_GLDS 1
#endif
#if __has_builtin(__builtin_amdgcn_exp2f)
#define EXP2(x) __builtin_amdgcn_exp2f(x)
#endif
#endif
#ifndef EXP2
#define EXP2(x) exp2f(x)
#endif

#ifdef HAVE_GLDS
#define GLDS16(g, l) __builtin_amdgcn_global_load_lds( \
    (const __attribute__((address_space(1))) void*)(g), \
    (__attribute__((address_space(3))) void*)(l), 16, 0, 0)
#endif

__device__ inline uint32_t pack2bf(float a, float b) {
  union { __bf16 h[2]; uint32_t u; } x;
  x.h[0] = (__bf16)a; x.h[1] = (__bf16)b;
  return x.u;
}

// ---------------- f32 -> bf16 vectorized convert ----------------
__global__ __launch_bounds__(256) void k_cvt_bf16(const float4* __restrict__ in,
                                                  bf16x4* __restrict__ out, int n4) {
  int i = blockIdx.x * 256 + threadIdx.x;
  if (i >= n4) return;
  float4 v = in[i];
  bf16x4 o;
  o[0] = (__bf16)v.x; o[1] = (__bf16)v.y; o[2] = (__bf16)v.z; o[3] = (__bf16)v.w;
  out[i] = o;
}

// ---------------- f32 [R][C] -> bf16 [C][R] transpose+convert ----------------
__global__ __launch_bounds__(256) void k_transpose_cvt(const float* __restrict__ in,
                                                       __bf16* __restrict__ out,
                                                       int R, int C) {
  __shared__ float tile[64][65];
  int r0 = blockIdx.y * 64, c0 = blockIdx.x * 64;
#pragma unroll
  for (int i = 0; i < 16; ++i) {
    int e = threadIdx.x + i * 256;
    int lr = e >> 6, lc = e & 63;
    tile[lr][lc] = in[(size_t)(r0 + lr) * C + c0 + lc];
  }
  __syncthreads();
#pragma unroll
  for (int i = 0; i < 16; ++i) {
    int e = threadIdx.x + i * 256;
    int lc = e >> 6, lr = e & 63;
    out[(size_t)(c0 + lc) * R + r0 + lr] = (__bf16)tile[lr][lc];
  }
}

// ---------------- bf16 GEMM: C[M][N] = A[M][K] @ Bt[N][K]^T + bias ----------------
template <int MODE>
__global__ __launch_bounds__(256) void k_gemm(const __bf16* __restrict__ A,
                                              const __bf16* __restrict__ Bt,
                                              const float* __restrict__ bias,
                                              float* __restrict__ Cf,
                                              __bf16* __restrict__ Qb,
                                              __bf16* __restrict__ Kb,
                                              __bf16* __restrict__ Vtmp,
                                              int K, int N) {
  __shared__ __bf16 lA[128 * 32];
  __shared__ __bf16 lB[128 * 32];
  const int tid = threadIdx.x;
  const int lane = tid & 63, w = tid >> 6;
  const int wr = w >> 1, wc = w & 1;
  const int r15 = lane & 15, rg = lane >> 4;
  const int mb = blockIdx.y, nb = blockIdx.x;
  const int nk = K >> 5;

  const f32x4 zero = {0.f, 0.f, 0.f, 0.f};
  f32x4 acc[4][4];
#pragma unroll
  for (int m = 0; m < 4; ++m)
#pragma unroll
    for (int n = 0; n < 4; ++n) acc[m][n] = zero;

  const int c0 = tid, c1 = tid + 256;
  const int rowA0 = c0 >> 2, offA0 = (c0 & 3) * 8;
  const int rowA1 = c1 >> 2, offA1 = (c1 & 3) * 8;
  const __bf16* Ab = A + (size_t)(mb * 128) * K;
  const __bf16* Bb = Bt + (size_t)(nb * 128) * K;

  for (int kb = 0; kb < nk; ++kb) {
    __syncthreads();
#ifdef HAVE_GLDS
    GLDS16(Ab + (size_t)rowA0 * K + kb * 32 + offA0, &lA[c0 * 8]);
    GLDS16(Ab + (size_t)rowA1 * K + kb * 32 + offA1, &lA[c1 * 8]);
    GLDS16(Bb + (size_t)rowA0 * K + kb * 32 + offA0, &lB[c0 * 8]);
    GLDS16(Bb + (size_t)rowA1 * K + kb * 32 + offA1, &lB[c1 * 8]);
#else
    {
      bf16x8 ta0 = *(const bf16x8*)(Ab + (size_t)rowA0 * K + kb * 32 + offA0);
      bf16x8 ta1 = *(const bf16x8*)(Ab + (size_t)rowA1 * K + kb * 32 + offA1);
      bf16x8 tb0 = *(const bf16x8*)(Bb + (size_t)rowA0 * K + kb * 32 + offA0);
      bf16x8 tb1 = *(const bf16x8*)(Bb + (size_t)rowA1 * K + kb * 32 + offA1);
      *(bf16x8*)(&lA[c0 * 8]) = ta0;
      *(bf16x8*)(&lA[c1 * 8]) = ta1;
      *(bf16x8*)(&lB[c0 * 8]) = tb0;
      *(bf16x8*)(&lB[c1 * 8]) = tb1;
    }
#endif
    __syncthreads();
    bf16x8 af[4], bfr[4];
#pragma unroll
    for (int m = 0; m < 4; ++m)
      af[m] = *(const bf16x8*)(&lA[(wr * 64 + m * 16 + r15) * 32 + rg * 8]);
#pragma unroll
    for (int n = 0; n < 4; ++n)
      bfr[n] = *(const bf16x8*)(&lB[(wc * 64 + n * 16 + r15) * 32 + rg * 8]);
#pragma unroll
    for (int m = 0; m < 4; ++m)
#pragma unroll
      for (int n = 0; n < 4; ++n)
        acc[m][n] = MFMA16(af[m], bfr[n], acc[m][n]);
  }

  const int row0 = mb * 128 + wr * 64;
  const int col0 = nb * 128 + wc * 64;
#pragma unroll
  for (int m = 0; m < 4; ++m) {
#pragma unroll
    for (int n = 0; n < 4; ++n) {
#pragma unroll
      for (int j = 0; j < 4; ++j) {
        int r = row0 + m * 16 + rg * 4 + j;
        int c = col0 + n * 16 + r15;
        float v = acc[m][n][j] + bias[c];
        if (MODE == 0) {
          Cf[(size_t)r * N + c] = v;
        } else {
          int which = c >> 10, cc = c & 1023;
          int b = r >> 11, t = r & 2047;
          if (which == 0) {
            int hh = cc >> 6, hd = cc & 63;
            Qb[((size_t)(b * H_ + hh) * T_ + t) * HD_ + hd] = (__bf16)(v * SCALE_Q);
          } else if (which == 1) {
            int hh = cc >> 6, hd = cc & 63;
            Kb[((size_t)(b * H_ + hh) * T_ + t) * HD_ + hd] = (__bf16)v;
          } else {
            Vtmp[(size_t)r * D_ + cc] = (__bf16)v;
          }
        }
      }
    }
  }
}

// ---------------- V transpose: Vtmp [B*T][D] -> Vt [B,H,HD,T] ----------------
__global__ __launch_bounds__(256) void k_vtrans(const __bf16* __restrict__ Vtmp,
                                                __bf16* __restrict__ Vt) {
  __shared__ __bf16 tile[64][72];
  const int bh = blockIdx.y;
  const int b = bh >> 4, h = bh & 15;
  const int t0 = blockIdx.x * 64;
  const int tid = threadIdx.x;
#pragma unroll
  for (int i = 0; i < 2; ++i) {
    int e = tid + i * 256;
    int tr = e >> 3, c8 = (e & 7) * 8;
    bf16x8 v = *(const bf16x8*)(Vtmp + (size_t)(b * T_ + t0 + tr) * D_ + h * HD_ + c8);
    *(bf16x8*)(&tile[tr][c8]) = v;
  }
  __syncthreads();
  const int hr = tid >> 2, tc0 = (tid & 3) * 16;
#pragma unroll
  for (int half = 0; half < 2; ++half) {
    bf16x8 o;
#pragma unroll
    for (int i = 0; i < 8; ++i) o[i] = tile[tc0 + half * 8 + i][hr];
    *(bf16x8*)(Vt + ((size_t)bh * HD_ + hr) * T_ + t0 + tc0 + half * 8) = o;
  }
}

// ---------------- flash attention (causal), 4-wave block, LDS-staged K/V ----------------
// grid (8, B*H), 256 threads. Block processes two 128-row Q supertiles: s=15-x
// (heavy) then s=x (light) -> constant 34 kv-steps/block. KVBLK=64. K,V tiles
// double-buffered in LDS (global_load_lds, XOR-swizzled chunks). Per wave:
// 32 q-rows, swapped 32x32 MFMA, in-register softmax (exp2 domain, defer-max).
__global__ __launch_bounds__(256) void k_attn(const __bf16* __restrict__ Qb,
                                              const __bf16* __restrict__ Kb,
                                              const __bf16* __restrict__ Vt,
                                              __bf16* __restrict__ Obuf) {
  __shared__ __bf16 lK[2][64 * 64];
  __shared__ __bf16 lV[2][64 * 64];
  const int tid = threadIdx.x;
  const int lane = tid & 63, w = tid >> 6;
  const int l31 = lane & 31, hi = lane >> 5;
  const int bh = blockIdx.y;
  const int b = bh >> 4, h = bh & 15;
  const __bf16* Qh = Qb + (size_t)bh * T_ * HD_;
  const __bf16* Kh = Kb + (size_t)bh * T_ * HD_;
  const __bf16* Vh = Vt + (size_t)bh * HD_ * T_;

  // staging geometry: 512 chunks (16B) per 64x64 tile, 2 per thread per tile.
  // LDS dest linear (chunk c -> bytes c*16); global src chunk = cc ^ (row&7)
  // (both-sides swizzle, rule #21). row stride = 64 bf16 = 128 B.
  const int sRow0 = tid >> 3, sCc0 = tid & 7;
  const int sRow1 = (tid + 256) >> 3, sCc1 = (tid + 256) & 7;
  const int sSw0 = (sCc0 ^ (sRow0 & 7)) * 8;
  const int sSw1 = (sCc1 ^ (sRow1 & 7)) * 8;

  auto STAGE = [&](int bufi, int kv0) {
#ifdef HAVE_GLDS
    GLDS16(Kh + (size_t)(kv0 + sRow0) * HD_ + sSw0, &lK[bufi][tid * 8]);
    GLDS16(Kh + (size_t)(kv0 + sRow1) * HD_ + sSw1, &lK[bufi][(tid + 256) * 8]);
    GLDS16(Vh + (size_t)sRow0 * T_ + kv0 + sSw0, &lV[bufi][tid * 8]);
    GLDS16(Vh + (size_t)sRow1 * T_ + kv0 + sSw1, &lV[bufi][(tid + 256) * 8]);
#else
    bf16x8 k0 = *(const bf16x8*)(Kh + (size_t)(kv0 + sRow0) * HD_ + sSw0);
    bf16x8 k1 = *(const bf16x8*)(Kh + (size_t)(kv0 + sRow1) * HD_ + sSw1);
    bf16x8 v0 = *(const bf16x8*)(Vh + (size_t)sRow0 * T_ + kv0 + sSw0);
    bf16x8 v1 = *(const bf16x8*)(Vh + (size_t)sRow1 * T_ + kv0 + sSw1);
    *(bf16x8*)(&lK[bufi][tid * 8]) = k0;
    *(bf16x8*)(&lK[bufi][(tid + 256) * 8]) = k1;
    *(bf16x8*)(&lV[bufi][tid * 8]) = v0;
    *(bf16x8*)(&lV[bufi][(tid + 256) * 8]) = v1;
#endif
  };

  int buf = 0;
  STAGE(0, 0);  // prologue: first tile of first half

  auto process_half = [&](int s, int nst, bool hasNext) {
    const int q0w = s * 128 + w * 32;
    // Q B-frags (col=q=l31, k = ks*16 + hi*8 + i), pre-scaled in GEMM epilogue
    bf16x8 qf[4];
#pragma unroll
    for (int ks = 0; ks < 4; ++ks)
      qf[ks] = *(const bf16x8*)(Qh + (size_t)(q0w + l31) * HD_ + ks * 16 + hi * 8);

    f32x16 o0, o1;
#pragma unroll
    for (int i = 0; i < 16; ++i) { o0[i] = 0.f; o1[i] = 0.f; }
    float mrun = -INFINITY, lrun = 0.f;

    for (int i = 0; i < nst; ++i) {
      const int kv0 = i * 64;
      if (i + 1 < nst) STAGE(buf ^ 1, (i + 1) * 64);
      else if (hasNext) STAGE(buf ^ 1, 0);

      if (kv0 <= q0w + 31) {  // wave-uniform: skip fully-masked tiles
        const bool masked = (kv0 + 63) > q0w;
        // K A-frags from LDS: row = seg*32+l31, chunk (ks*2+hi)^(row&7)
        bf16x8 kf[2][4];
#pragma unroll
        for (int seg = 0; seg < 2; ++seg)
#pragma unroll
          for (int ks = 0; ks < 4; ++ks)
            kf[seg][ks] = *(const bf16x8*)(&lK[buf][(seg * 32 + l31) * 64 +
                                                   (((ks * 2 + hi) ^ (l31 & 7)) * 8)]);
        f32x16 s0, s1;
#pragma unroll
        for (int r = 0; r < 16; ++r) { s0[r] = 0.f; s1[r] = 0.f; }
#pragma unroll
        for (int ks = 0; ks < 4; ++ks) s0 = MFMA32(kf[0][ks], qf[ks], s0);
#pragma unroll
        for (int ks = 0; ks < 4; ++ks) s1 = MFMA32(kf[1][ks], qf[ks], s1);

        if (masked) {
#pragma unroll
          for (int r = 0; r < 16; ++r) {
            int rr = (r & 3) + 8 * (r >> 2) + 4 * hi;
            if (kv0 + rr > q0w + l31) s0[r] = -INFINITY;
            if (kv0 + 32 + rr > q0w + l31) s1[r] = -INFINITY;
          }
        }
        float pmax = -INFINITY;
#pragma unroll
        for (int r = 0; r < 16; ++r) pmax = fmaxf(pmax, fmaxf(s0[r], s1[r]));
        pmax = fmaxf(pmax, __shfl_xor(pmax, 32, 64));

        if (__any(pmax > mrun + 8.0f)) {  // defer-max (T13)
          float mnew = fmaxf(mrun, pmax);
          float sc = EXP2(mrun - mnew);   // first tile: exp2(-inf) = 0
#pragma unroll
          for (int r = 0; r < 16; ++r) {
            int rr = (r & 3) + 8 * (r >> 2) + 4 * hi;
            float scr = __shfl(sc, rr, 64);
            o0[r] *= scr; o1[r] *= scr;
          }
          lrun *= sc;
          mrun = mnew;
        }
        float rs = 0.f;
#pragma unroll
        for (int r = 0; r < 16; ++r) {
          s0[r] = EXP2(s0[r] - mrun); s1[r] = EXP2(s1[r] - mrun);
          rs += s0[r] + s1[r];
        }
        rs += __shfl_xor(rs, 32, 64);
        lrun += rs;

        // V B-frags from LDS: tile row = d = dh*32+l31
        bf16x8 vf[2][4];
#pragma unroll
        for (int dh = 0; dh < 2; ++dh)
#pragma unroll
          for (int ks = 0; ks < 4; ++ks)
            vf[dh][ks] = *(const bf16x8*)(&lV[buf][(dh * 32 + l31) * 64 +
                                                   (((ks * 2 + hi) ^ (l31 & 7)) * 8)]);

        // P repack -> A-frags (partner exchange via shfl_xor 32); p = s0|s1
#pragma unroll
        for (int ks = 0; ks < 4; ++ks) {
          const f32x16& sv = (ks < 2) ? s0 : s1;
          const int off = (ks & 1) * 8;
          uint32_t w0 = pack2bf(sv[off + 0], sv[off + 1]);
          uint32_t w1 = pack2bf(sv[off + 2], sv[off + 3]);
          uint32_t w2 = pack2bf(sv[off + 4], sv[off + 5]);
          uint32_t w3 = pack2bf(sv[off + 6], sv[off + 7]);
          uint32_t sx = hi ? w0 : w2;
          uint32_t sy = hi ? w1 : w3;
          uint32_t px = (uint32_t)__shfl_xor((int)sx, 32, 64);
          uint32_t py = (uint32_t)__shfl_xor((int)sy, 32, 64);
          union { uint32_t u[4]; bf16x8 v; } pa;
          pa.u[0] = hi ? px : w0;
          pa.u[1] = hi ? py : w1;
          pa.u[2] = hi ? w2 : px;
          pa.u[3] = hi ? w3 : py;
          o0 = MFMA32(pa.v, vf[0][ks], o0);
          o1 = MFMA32(pa.v, vf[1][ks], o1);
        }
      }
      __syncthreads();  // drains staging vmcnt + all waves done with buf
      buf ^= 1;
    }

    // epilogue: row q' = rr(r,hi), col d = l31 (+32)
#pragma unroll
    for (int r = 0; r < 16; ++r) {
      int rr = (r & 3) + 8 * (r >> 2) + 4 * hi;
      float inv = 1.0f / __shfl(lrun, rr, 64);
      int row = q0w + rr;
      __bf16* op = Obuf + (size_t)(b * T_ + row) * D_ + h * HD_ + l31;
      op[0]  = (__bf16)(o0[r] * inv);
      op[32] = (__bf16)(o1[r] * inv);
    }
  };

  const int sA = 15 - blockIdx.x;      // heavy half first
  const int sB = blockIdx.x;
  __syncthreads();                     // prologue stage visible
  process_half(sA, 2 * sA + 2, true);
  process_half(sB, 2 * sB + 2, false);
}

// ---------------- launcher ----------------
extern "C" void kernel_launch(void* const* d_in, const int* in_sizes, int n_in,
                              void* d_out, int out_size, void* d_ws, size_t ws_size,
                              hipStream_t stream) {
  const float* x      = (const float*)d_in[0];
  const float* W_qkv  = (const float*)d_in[1];
  const float* b_qkv  = (const float*)d_in[2];
  const float* W_proj = (const float*)d_in[3];
  const float* b_proj = (const float*)d_in[4];
  float* out = (float*)d_out;

  char* ws = (char*)d_ws;
  size_t o = 0;
  __bf16* xb     = (__bf16*)(ws + o); o += (size_t)M_ * D_ * 2;
  __bf16* wqkvt  = (__bf16*)(ws + o); o += (size_t)NQKV_ * D_ * 2;
  __bf16* wprojt = (__bf16*)(ws + o); o += (size_t)D_ * D_ * 2;
  __bf16* Qb     = (__bf16*)(ws + o); o += (size_t)M_ * D_ * 2;
  __bf16* Kb     = (__bf16*)(ws + o); o += (size_t)M_ * D_ * 2;
  __bf16* Vtmp   = (__bf16*)(ws + o); o += (size_t)M_ * D_ * 2;
  __bf16* Vt     = (__bf16*)(ws + o); o += (size_t)M_ * D_ * 2;
  __bf16* Obuf   = (__bf16*)(ws + o); o += (size_t)M_ * D_ * 2;
  (void)ws_size; (void)in_sizes; (void)n_in; (void)out_size;

  k_cvt_bf16<<<(M_ * D_ / 4 + 255) / 256, 256, 0, stream>>>((const float4*)x, (bf16x4*)xb, M_ * D_ / 4);
  k_transpose_cvt<<<dim3(NQKV_ / 64, D_ / 64), 256, 0, stream>>>(W_qkv, wqkvt, D_, NQKV_);
  k_transpose_cvt<<<dim3(D_ / 64, D_ / 64), 256, 0, stream>>>(W_proj, wprojt, D_, D_);
  k_gemm<1><<<dim3(NQKV_ / 128, M_ / 128), 256, 0, stream>>>(xb, wqkvt, b_qkv, nullptr, Qb, Kb, Vtmp, D_, NQKV_);
  k_vtrans<<<dim3(T_ / 64, B_ * H_), 256, 0, stream>>>(Vtmp, Vt);
  k_attn<<<dim3(8, B_ * H_), 256, 0, stream>>>(Qb, Kb, Vt, Obuf);
  k_gemm<0><<<dim3(D_ / 128, M_ / 128), 256, 0, stream>>>(Obuf, wprojt, b_proj, out, nullptr, nullptr, nullptr, D_, D_);
}